// Round 4
// baseline (860.795 us; speedup 1.0000x reference)
//
#include <hip/hip_runtime.h>
#include <hip/hip_bf16.h>

#define NN 100000
#define EE 1000000
#define GG 128
#define EMB 128
#define HH 64
#define LL 3
#define TT 2
#define BN_EPS 1e-5f

// workspace float offsets
#define X_OFF     0L
#define AGG_OFF   6400000L
#define WT1_OFF   12800000L   // fh layer1: scaled cols [128][64]
#define C1_OFF    12808192L
#define WT2_OFF   12808256L   // fh layer2: scaled cols [64][64]
#define C2_OFF    12812352L
#define WTC1_OFF  12812416L   // conv layer1 (x3): scaled cols [64][64]
#define CC1_OFF   12824704L
#define WTC2_OFF  12824896L   // conv layer2 (x3): scaled cols [64][64]
#define CC2_OFF   12837184L
#define POOL_OFF  12837376L   // 4 stages * 128 * 64
#define CNT_OFF   12870144L   // 128 floats
// CSR region (int-typed views into ws)
#define COL_OFF   12870400L   // 1,000,000 ints
#define CUR_OFF   13870400L   // 100,000 ints: counts -> exclusive starts -> ends
#define BSUM_OFF  13970432L   // 128 ints (block partials for scan)

#define SCAN_BLK 1024
#define SCAN_NBLK ((NN + SCAN_BLK - 1) / SCAN_BLK)   // 98

// ---------------- prep: fold BN scale into weight columns ----------------
__global__ void prep_kernel(
    const float* __restrict__ fh_W1, const float* __restrict__ fh_b1, const float* __restrict__ fh_g1,
    const float* __restrict__ fh_bt1, const float* __restrict__ fh_m1, const float* __restrict__ fh_v1,
    const float* __restrict__ fh_W2, const float* __restrict__ fh_b2, const float* __restrict__ fh_g2,
    const float* __restrict__ fh_bt2, const float* __restrict__ fh_m2, const float* __restrict__ fh_v2,
    const float* __restrict__ cW1, const float* __restrict__ cb1, const float* __restrict__ cg1,
    const float* __restrict__ cbt1, const float* __restrict__ cm1, const float* __restrict__ cv1,
    const float* __restrict__ cW2, const float* __restrict__ cb2, const float* __restrict__ cg2,
    const float* __restrict__ cbt2, const float* __restrict__ cm2, const float* __restrict__ cv2,
    float* __restrict__ ws)
{
    int job = blockIdx.x;
    const float *W, *b, *g, *bt, *m, *v;
    float *Wo, *Co;
    int K;
    if (job == 0) {
        W = fh_W1; b = fh_b1; g = fh_g1; bt = fh_bt1; m = fh_m1; v = fh_v1;
        Wo = ws + WT1_OFF; Co = ws + C1_OFF; K = 128;
    } else if (job == 1) {
        W = fh_W2; b = fh_b2; g = fh_g2; bt = fh_bt2; m = fh_m2; v = fh_v2;
        Wo = ws + WT2_OFF; Co = ws + C2_OFF; K = 64;
    } else if (job <= 4) {
        int l = job - 2;
        W = cW1 + l * 4096; b = cb1 + l * 64; g = cg1 + l * 64; bt = cbt1 + l * 64;
        m = cm1 + l * 64; v = cv1 + l * 64;
        Wo = ws + WTC1_OFF + l * 4096; Co = ws + CC1_OFF + l * 64; K = 64;
    } else {
        int l = job - 5;
        W = cW2 + l * 4096; b = cb2 + l * 64; g = cg2 + l * 64; bt = cbt2 + l * 64;
        m = cm2 + l * 64; v = cv2 + l * 64;
        Wo = ws + WTC2_OFF + l * 4096; Co = ws + CC2_OFF + l * 64; K = 64;
    }
    int tot = 64 * K;
    for (int i = threadIdx.x; i < tot; i += blockDim.x) {
        int j = i & 63;
        float s = g[j] * rsqrtf(v[j] + BN_EPS);
        Wo[i] = W[i] * s;   // keep [k][j] layout, scale column j
    }
    if (threadIdx.x < 64) {
        int j = threadIdx.x;
        float s = g[j] * rsqrtf(v[j] + BN_EPS);
        Co[j] = (b[j] - m[j]) * s + bt[j];
    }
}

// ---------------- CSR build ----------------
__global__ __launch_bounds__(256) void hist_kernel(const int* __restrict__ edges, int* __restrict__ cnt)
{
    int e = blockIdx.x * blockDim.x + threadIdx.x;
    if (e >= EE) return;
    atomicAdd(&cnt[edges[EE + e]], 1);
}

__global__ __launch_bounds__(SCAN_BLK) void scan_pass1(const int* __restrict__ cnt, int* __restrict__ bsum)
{
    __shared__ int r[SCAN_BLK];
    int t = threadIdx.x;
    int i = blockIdx.x * SCAN_BLK + t;
    r[t] = (i < NN) ? cnt[i] : 0;
    __syncthreads();
    for (int off = SCAN_BLK / 2; off > 0; off >>= 1) {
        if (t < off) r[t] += r[t + off];
        __syncthreads();
    }
    if (t == 0) bsum[blockIdx.x] = r[0];
}

__global__ __launch_bounds__(128) void scan_pass2(int* __restrict__ bsum)
{
    __shared__ int s[128];
    int t = threadIdx.x;
    int v = (t < SCAN_NBLK) ? bsum[t] : 0;
    s[t] = v;
    __syncthreads();
    for (int off = 1; off < 128; off <<= 1) {
        int a = (t >= off) ? s[t - off] : 0;
        __syncthreads();
        s[t] += a;
        __syncthreads();
    }
    if (t < SCAN_NBLK) bsum[t] = s[t] - v;   // exclusive
}

__global__ __launch_bounds__(SCAN_BLK) void scan_pass3(int* __restrict__ cnt, const int* __restrict__ bsum)
{
    __shared__ int s[SCAN_BLK];
    int t = threadIdx.x;
    int i = blockIdx.x * SCAN_BLK + t;
    int v = (i < NN) ? cnt[i] : 0;
    s[t] = v;
    __syncthreads();
    for (int off = 1; off < SCAN_BLK; off <<= 1) {
        int a = (t >= off) ? s[t - off] : 0;
        __syncthreads();
        s[t] += a;
        __syncthreads();
    }
    if (i < NN) cnt[i] = bsum[blockIdx.x] + s[t] - v;   // exclusive start
}

__global__ __launch_bounds__(256) void fill_kernel(
    const int* __restrict__ edges, int* __restrict__ cursor, int* __restrict__ col)
{
    int e = blockIdx.x * blockDim.x + threadIdx.x;
    if (e >= EE) return;
    int dst = edges[EE + e];
    int p = atomicAdd(&cursor[dst], 1);
    col[p] = edges[e];
}
// after fill: cursor[n] == row end for node n; row start = (n==0)?0:cursor[n-1]

// ---------------- gather: agg = x + sum_{src in N(n)} x[src]  (wave per node) ----------------
__global__ __launch_bounds__(256) void gather_kernel(
    const float* __restrict__ x, const int* __restrict__ cursor, const int* __restrict__ col,
    float* __restrict__ aggout)
{
    int wid = (blockIdx.x * blockDim.x + threadIdx.x) >> 6;
    int lane = threadIdx.x & 63;
    if (wid >= NN) return;
    int start = (wid == 0) ? 0 : cursor[wid - 1];
    int end = cursor[wid];
    float acc = x[(long)wid * 64 + lane];
    for (int base = start; base < end; base += 64) {
        int m = end - base; if (m > 64) m = 64;
        int idx = (lane < m) ? col[base + lane] : 0;
        for (int j = 0; j < m; ++j) {
            int s = __shfl(idx, j);
            acc += x[(long)s * 64 + lane];
        }
    }
    aggout[(long)wid * 64 + lane] = acc;
}

// ---------------- embedding gather + layer1 (thread = node, 64 accumulators) ----------------
__global__ __attribute__((amdgpu_waves_per_eu(2, 4))) __launch_bounds__(256)
void embed_l1_kernel(
    const int* __restrict__ node_ids, const float* __restrict__ emb,
    const float* __restrict__ Ws, const float* __restrict__ Cv,
    float* __restrict__ hout)
{
    int n = blockIdx.x * blockDim.x + threadIdx.x;
    if (n >= NN) return;
    long nid = node_ids[n];
    const float4* i4 = (const float4*)(emb + nid * 128);

    float a[64];
#pragma unroll
    for (int j = 0; j < 64; j++) a[j] = Cv[j];
#pragma unroll 4
    for (int q = 0; q < 32; q++) {
        float4 t = i4[q];
        const float* w = Ws + q * 4 * 64;
#pragma unroll
        for (int j = 0; j < 64; j++) a[j] += t.x * w[j];
#pragma unroll
        for (int j = 0; j < 64; j++) a[j] += t.y * w[64 + j];
#pragma unroll
        for (int j = 0; j < 64; j++) a[j] += t.z * w[128 + j];
#pragma unroll
        for (int j = 0; j < 64; j++) a[j] += t.w * w[192 + j];
    }
    float4* o4 = (float4*)(hout + (long)n * 64);
#pragma unroll
    for (int q = 0; q < 16; q++) {
        float4 t;
        t.x = fmaxf(a[4*q+0], 0.f); t.y = fmaxf(a[4*q+1], 0.f);
        t.z = fmaxf(a[4*q+2], 0.f); t.w = fmaxf(a[4*q+3], 0.f);
        o4[q] = t;
    }
}

// ---------------- generic 64->64 layer + relu (thread = node; safe in-place) ----------------
__global__ __attribute__((amdgpu_waves_per_eu(2, 4))) __launch_bounds__(256)
void mlp64_kernel(
    const float* __restrict__ in, const float* __restrict__ Ws,
    const float* __restrict__ Cv, float* __restrict__ outbuf)
{
    int n = blockIdx.x * blockDim.x + threadIdx.x;
    if (n >= NN) return;
    const float4* i4 = (const float4*)(in + (long)n * 64);

    float a[64];
#pragma unroll
    for (int j = 0; j < 64; j++) a[j] = Cv[j];
#pragma unroll 4
    for (int q = 0; q < 16; q++) {
        float4 t = i4[q];
        const float* w = Ws + q * 4 * 64;
#pragma unroll
        for (int j = 0; j < 64; j++) a[j] += t.x * w[j];
#pragma unroll
        for (int j = 0; j < 64; j++) a[j] += t.y * w[64 + j];
#pragma unroll
        for (int j = 0; j < 64; j++) a[j] += t.z * w[128 + j];
#pragma unroll
        for (int j = 0; j < 64; j++) a[j] += t.w * w[192 + j];
    }
    float4* o4 = (float4*)(outbuf + (long)n * 64);
#pragma unroll
    for (int q = 0; q < 16; q++) {
        float4 t;
        t.x = fmaxf(a[4*q+0], 0.f); t.y = fmaxf(a[4*q+1], 0.f);
        t.z = fmaxf(a[4*q+2], 0.f); t.w = fmaxf(a[4*q+3], 0.f);
        o4[q] = t;
    }
}

// ---------------- graph pooling over sorted batch (wave per node range) ----------------
#define POOL_WAVES 4096
#define POOL_CHUNK ((NN + POOL_WAVES - 1) / POOL_WAVES)
__global__ __launch_bounds__(256) void pool_kernel(
    const float* __restrict__ x, const int* __restrict__ batch,
    float* __restrict__ pooled, float* __restrict__ cnt)
{
    int wave = (blockIdx.x * blockDim.x + threadIdx.x) >> 6;
    int lane = threadIdx.x & 63;
    int start = wave * POOL_CHUNK;
    int end = start + POOL_CHUNK;
    if (end > NN) end = NN;
    if (start >= end) return;
    int g_cur = batch[start];
    float acc = 0.f, c = 0.f;
    for (int n = start; n < end; ++n) {
        int g = batch[n];
        if (g != g_cur) {
            unsafeAtomicAdd(&pooled[(long)g_cur * 64 + lane], acc);
            if (cnt != nullptr && lane == 0) unsafeAtomicAdd(&cnt[g_cur], c);
            acc = 0.f; c = 0.f; g_cur = g;
        }
        acc += x[(long)n * 64 + lane];
        c += 1.f;
    }
    unsafeAtomicAdd(&pooled[(long)g_cur * 64 + lane], acc);
    if (cnt != nullptr && lane == 0) unsafeAtomicAdd(&cnt[g_cur], c);
}

// ---------------- readout + softmax ----------------
__global__ void final_kernel(
    const float* __restrict__ pooled, const float* __restrict__ cnt,
    const float* __restrict__ linW, const float* __restrict__ linb,
    float* __restrict__ outp)
{
    int g = threadIdx.x;
    if (g >= GG) return;
    float z0 = 0.f, z1 = 0.f;
    float c = cnt[g];
    for (int l = 0; l < 4; l++) {
        const float* p = pooled + (long)l * GG * 64 + (long)g * 64;
        const float* W = linW + l * 128;
        float s0 = linb[l * 2 + 0] * c;
        float s1 = linb[l * 2 + 1] * c;
        for (int k = 0; k < 64; k++) {
            float pk = p[k];
            s0 += pk * W[k * 2 + 0];
            s1 += pk * W[k * 2 + 1];
        }
        z0 += s0; z1 += s1;
    }
    float mx = fmaxf(z0, z1);
    float e0 = expf(z0 - mx), e1 = expf(z1 - mx);
    float inv = 1.f / (e0 + e1);
    outp[g * 2 + 0] = e0 * inv;
    outp[g * 2 + 1] = e1 * inv;
}

extern "C" void kernel_launch(void* const* d_in, const int* in_sizes, int n_in,
                              void* d_out, int out_size, void* d_ws, size_t ws_size,
                              hipStream_t stream) {
    const int*   node_ids = (const int*)d_in[0];
    const int*   edges    = (const int*)d_in[1];
    const int*   batch    = (const int*)d_in[2];
    const float* emb      = (const float*)d_in[3];
    const float* fh_W1 = (const float*)d_in[4];
    const float* fh_b1 = (const float*)d_in[5];
    const float* fh_g1 = (const float*)d_in[6];
    const float* fh_bt1 = (const float*)d_in[7];
    const float* fh_m1 = (const float*)d_in[8];
    const float* fh_v1 = (const float*)d_in[9];
    const float* fh_W2 = (const float*)d_in[10];
    const float* fh_b2 = (const float*)d_in[11];
    const float* fh_g2 = (const float*)d_in[12];
    const float* fh_bt2 = (const float*)d_in[13];
    const float* fh_m2 = (const float*)d_in[14];
    const float* fh_v2 = (const float*)d_in[15];
    const float* cW1 = (const float*)d_in[16];
    const float* cb1 = (const float*)d_in[17];
    const float* cg1 = (const float*)d_in[18];
    const float* cbt1 = (const float*)d_in[19];
    const float* cm1 = (const float*)d_in[20];
    const float* cv1 = (const float*)d_in[21];
    const float* cW2 = (const float*)d_in[22];
    const float* cb2 = (const float*)d_in[23];
    const float* cg2 = (const float*)d_in[24];
    const float* cbt2 = (const float*)d_in[25];
    const float* cm2 = (const float*)d_in[26];
    const float* cv2 = (const float*)d_in[27];
    const float* linW = (const float*)d_in[28];
    const float* linb = (const float*)d_in[29];

    float* ws = (float*)d_ws;
    int* cursor = (int*)(ws + CUR_OFF);
    int* col    = (int*)(ws + COL_OFF);
    int* bsum   = (int*)(ws + BSUM_OFF);

    prep_kernel<<<8, 256, 0, stream>>>(
        fh_W1, fh_b1, fh_g1, fh_bt1, fh_m1, fh_v1,
        fh_W2, fh_b2, fh_g2, fh_bt2, fh_m2, fh_v2,
        cW1, cb1, cg1, cbt1, cm1, cv1,
        cW2, cb2, cg2, cbt2, cm2, cv2, ws);

    // zero pooled + cnt, and the CSR histogram counters
    hipMemsetAsync(ws + POOL_OFF, 0, (4L * GG * 64 + GG) * sizeof(float), stream);
    hipMemsetAsync(cursor, 0, NN * sizeof(int), stream);

    // CSR build (dst-indexed)
    hist_kernel<<<(EE + 255) / 256, 256, 0, stream>>>(edges, cursor);
    scan_pass1<<<SCAN_NBLK, SCAN_BLK, 0, stream>>>(cursor, bsum);
    scan_pass2<<<1, 128, 0, stream>>>(bsum);
    scan_pass3<<<SCAN_NBLK, SCAN_BLK, 0, stream>>>(cursor, bsum);
    fill_kernel<<<(EE + 255) / 256, 256, 0, stream>>>(edges, cursor, col);

    const int NBLK = (NN + 255) / 256;

    // first MLP: emb-gather + L1 -> X (h), then L2 in-place X -> X
    embed_l1_kernel<<<NBLK, 256, 0, stream>>>(
        node_ids, emb, ws + WT1_OFF, ws + C1_OFF, ws + X_OFF);
    mlp64_kernel<<<NBLK, 256, 0, stream>>>(
        ws + X_OFF, ws + WT2_OFF, ws + C2_OFF, ws + X_OFF);

    pool_kernel<<<POOL_WAVES / 4, 256, 0, stream>>>(
        ws + X_OFF, batch, ws + POOL_OFF, ws + CNT_OFF);

    for (int l = 0; l < LL; l++) {
        gather_kernel<<<(NN * 64 + 255) / 256, 256, 0, stream>>>(
            ws + X_OFF, cursor, col, ws + AGG_OFF);
        // conv layer1: AGG -> AGG (in-place, per-row), conv layer2: AGG -> X
        mlp64_kernel<<<NBLK, 256, 0, stream>>>(
            ws + AGG_OFF, ws + WTC1_OFF + l * 4096, ws + CC1_OFF + l * 64, ws + AGG_OFF);
        mlp64_kernel<<<NBLK, 256, 0, stream>>>(
            ws + AGG_OFF, ws + WTC2_OFF + l * 4096, ws + CC2_OFF + l * 64, ws + X_OFF);
        pool_kernel<<<POOL_WAVES / 4, 256, 0, stream>>>(
            ws + X_OFF, batch, ws + POOL_OFF + (long)(l + 1) * GG * 64, nullptr);
    }

    final_kernel<<<1, 128, 0, stream>>>(
        ws + POOL_OFF, ws + CNT_OFF, linW, linb, (float*)d_out);
}

// Round 5
// 706.617 us; speedup vs baseline: 1.2182x; 1.2182x over previous
//
#include <hip/hip_runtime.h>
#include <hip/hip_bf16.h>

#define NN 100000
#define EE 1000000
#define GG 128
#define EMB 128
#define HH 64
#define LL 3
#define TT 2
#define BN_EPS 1e-5f

// workspace float offsets
#define X_OFF     0L
#define AGG_OFF   6400000L
#define WT1_OFF   12800000L   // fh layer1: scaled cols [128][64]
#define C1_OFF    12808192L
#define WT2_OFF   12808256L   // fh layer2: scaled cols [64][64]
#define C2_OFF    12812352L
#define WTC1_OFF  12812416L   // conv layer1 (x3): scaled cols [64][64]
#define CC1_OFF   12824704L
#define WTC2_OFF  12824896L   // conv layer2 (x3): scaled cols [64][64]
#define CC2_OFF   12837184L
#define POOL_OFF  12837376L   // 4 stages * 128 * 64
#define CNT_OFF   12870144L   // 128 floats
// CSR region (int-typed views into ws)
#define COL_OFF   12870400L   // 1,000,000 ints
#define CUR_OFF   13870400L   // 100,000 ints: counts -> exclusive starts -> ends
#define BSUM_OFF  13970432L   // 128 ints (block partials for scan)

#define SCAN_BLK 1024
#define SCAN_NBLK ((NN + SCAN_BLK - 1) / SCAN_BLK)   // 98

// ---------------- prep: fold BN scale into weight columns ----------------
__global__ void prep_kernel(
    const float* __restrict__ fh_W1, const float* __restrict__ fh_b1, const float* __restrict__ fh_g1,
    const float* __restrict__ fh_bt1, const float* __restrict__ fh_m1, const float* __restrict__ fh_v1,
    const float* __restrict__ fh_W2, const float* __restrict__ fh_b2, const float* __restrict__ fh_g2,
    const float* __restrict__ fh_bt2, const float* __restrict__ fh_m2, const float* __restrict__ fh_v2,
    const float* __restrict__ cW1, const float* __restrict__ cb1, const float* __restrict__ cg1,
    const float* __restrict__ cbt1, const float* __restrict__ cm1, const float* __restrict__ cv1,
    const float* __restrict__ cW2, const float* __restrict__ cb2, const float* __restrict__ cg2,
    const float* __restrict__ cbt2, const float* __restrict__ cm2, const float* __restrict__ cv2,
    float* __restrict__ ws)
{
    int job = blockIdx.x;
    const float *W, *b, *g, *bt, *m, *v;
    float *Wo, *Co;
    int K;
    if (job == 0) {
        W = fh_W1; b = fh_b1; g = fh_g1; bt = fh_bt1; m = fh_m1; v = fh_v1;
        Wo = ws + WT1_OFF; Co = ws + C1_OFF; K = 128;
    } else if (job == 1) {
        W = fh_W2; b = fh_b2; g = fh_g2; bt = fh_bt2; m = fh_m2; v = fh_v2;
        Wo = ws + WT2_OFF; Co = ws + C2_OFF; K = 64;
    } else if (job <= 4) {
        int l = job - 2;
        W = cW1 + l * 4096; b = cb1 + l * 64; g = cg1 + l * 64; bt = cbt1 + l * 64;
        m = cm1 + l * 64; v = cv1 + l * 64;
        Wo = ws + WTC1_OFF + l * 4096; Co = ws + CC1_OFF + l * 64; K = 64;
    } else {
        int l = job - 5;
        W = cW2 + l * 4096; b = cb2 + l * 64; g = cg2 + l * 64; bt = cbt2 + l * 64;
        m = cm2 + l * 64; v = cv2 + l * 64;
        Wo = ws + WTC2_OFF + l * 4096; Co = ws + CC2_OFF + l * 64; K = 64;
    }
    int tot = 64 * K;
    for (int i = threadIdx.x; i < tot; i += blockDim.x) {
        int j = i & 63;
        float s = g[j] * rsqrtf(v[j] + BN_EPS);
        Wo[i] = W[i] * s;   // keep [k][j] layout, scale column j
    }
    if (threadIdx.x < 64) {
        int j = threadIdx.x;
        float s = g[j] * rsqrtf(v[j] + BN_EPS);
        Co[j] = (b[j] - m[j]) * s + bt[j];
    }
}

// ---------------- CSR build ----------------
__global__ __launch_bounds__(256) void hist_kernel(const int* __restrict__ edges, int* __restrict__ cnt)
{
    int e = blockIdx.x * blockDim.x + threadIdx.x;
    if (e >= EE) return;
    atomicAdd(&cnt[edges[EE + e]], 1);
}

__global__ __launch_bounds__(SCAN_BLK) void scan_pass1(const int* __restrict__ cnt, int* __restrict__ bsum)
{
    __shared__ int r[SCAN_BLK];
    int t = threadIdx.x;
    int i = blockIdx.x * SCAN_BLK + t;
    r[t] = (i < NN) ? cnt[i] : 0;
    __syncthreads();
    for (int off = SCAN_BLK / 2; off > 0; off >>= 1) {
        if (t < off) r[t] += r[t + off];
        __syncthreads();
    }
    if (t == 0) bsum[blockIdx.x] = r[0];
}

__global__ __launch_bounds__(128) void scan_pass2(int* __restrict__ bsum)
{
    __shared__ int s[128];
    int t = threadIdx.x;
    int v = (t < SCAN_NBLK) ? bsum[t] : 0;
    s[t] = v;
    __syncthreads();
    for (int off = 1; off < 128; off <<= 1) {
        int a = (t >= off) ? s[t - off] : 0;
        __syncthreads();
        s[t] += a;
        __syncthreads();
    }
    if (t < SCAN_NBLK) bsum[t] = s[t] - v;   // exclusive
}

__global__ __launch_bounds__(SCAN_BLK) void scan_pass3(int* __restrict__ cnt, const int* __restrict__ bsum)
{
    __shared__ int s[SCAN_BLK];
    int t = threadIdx.x;
    int i = blockIdx.x * SCAN_BLK + t;
    int v = (i < NN) ? cnt[i] : 0;
    s[t] = v;
    __syncthreads();
    for (int off = 1; off < SCAN_BLK; off <<= 1) {
        int a = (t >= off) ? s[t - off] : 0;
        __syncthreads();
        s[t] += a;
        __syncthreads();
    }
    if (i < NN) cnt[i] = bsum[blockIdx.x] + s[t] - v;   // exclusive start
}

__global__ __launch_bounds__(256) void fill_kernel(
    const int* __restrict__ edges, int* __restrict__ cursor, int* __restrict__ col)
{
    int e = blockIdx.x * blockDim.x + threadIdx.x;
    if (e >= EE) return;
    int dst = edges[EE + e];
    int p = atomicAdd(&cursor[dst], 1);
    col[p] = edges[e];
}
// after fill: cursor[n] == row end for node n; row start = (n==0)?0:cursor[n-1]

// ---------------- gather: agg = x + sum_{src} x[src]; quarter-wave per neighbor ----------------
__global__ __launch_bounds__(256) void gather_kernel(
    const float* __restrict__ x, const int* __restrict__ cursor, const int* __restrict__ col,
    float* __restrict__ aggout)
{
    int wid = (blockIdx.x * blockDim.x + threadIdx.x) >> 6;
    if (wid >= NN) return;
    int lane = threadIdx.x & 63;
    int q = lane >> 4;        // quarter 0..3: which neighbor slot
    int c = lane & 15;        // which float4 of the row
    int start = (wid == 0) ? 0 : cursor[wid - 1];
    int end = cursor[wid];
    const float4* x4 = (const float4*)x;
    float4 acc;
    if (q == 0) acc = x4[(long)wid * 16 + c];               // += own row (GIN eps=0)
    else { acc.x = 0.f; acc.y = 0.f; acc.z = 0.f; acc.w = 0.f; }
    for (int b = start; b < end; b += 4) {
        int j = b + q;
        if (j < end) {
            int s = col[j];
            float4 t = x4[(long)s * 16 + c];
            acc.x += t.x; acc.y += t.y; acc.z += t.z; acc.w += t.w;
        }
    }
    // fold the 4 quarters
    acc.x += __shfl_xor(acc.x, 16); acc.y += __shfl_xor(acc.y, 16);
    acc.z += __shfl_xor(acc.z, 16); acc.w += __shfl_xor(acc.w, 16);
    acc.x += __shfl_xor(acc.x, 32); acc.y += __shfl_xor(acc.y, 32);
    acc.z += __shfl_xor(acc.z, 32); acc.w += __shfl_xor(acc.w, 32);
    if (q == 0) ((float4*)aggout)[(long)wid * 16 + c] = acc;
}

// ---------------- fused 2-layer MLP on a 128-row tile, LDS-staged ----------------
// buf row stride 65 floats: conflict-free per-thread row access.
__global__ __launch_bounds__(128) void conv_mlp2_kernel(
    const float* __restrict__ in,
    const float* __restrict__ W1s, const float* __restrict__ C1v,
    const float* __restrict__ W2s, const float* __restrict__ C2v,
    float* __restrict__ xout)
{
    __shared__ float buf[128 * 65];
    int tid = threadIdx.x;
    int row0 = blockIdx.x * 128;
    long gbase = (long)row0 * 64;
    const float4* g4 = (const float4*)(in + gbase);
    // coalesced stage-in
    for (int i = tid; i < 2048; i += 128) {
        int r = i >> 4, c = (i & 15) * 4;
        if (row0 + r < NN) {
            float4 t = g4[i];
            float* p = buf + r * 65 + c;
            p[0] = t.x; p[1] = t.y; p[2] = t.z; p[3] = t.w;
        }
    }
    __syncthreads();
    float* row = buf + tid * 65;
    // layer 1
    float a[64];
#pragma unroll
    for (int j = 0; j < 64; j++) a[j] = C1v[j];
    for (int k = 0; k < 64; k += 4) {
        float h0 = row[k], h1 = row[k + 1], h2 = row[k + 2], h3 = row[k + 3];
        const float* w = W1s + k * 64;
#pragma unroll
        for (int j = 0; j < 64; j++) a[j] += h0 * w[j];
#pragma unroll
        for (int j = 0; j < 64; j++) a[j] += h1 * w[64 + j];
#pragma unroll
        for (int j = 0; j < 64; j++) a[j] += h2 * w[128 + j];
#pragma unroll
        for (int j = 0; j < 64; j++) a[j] += h3 * w[192 + j];
    }
#pragma unroll
    for (int j = 0; j < 64; j++) row[j] = fmaxf(a[j], 0.f);   // own row only: no barrier needed
    // layer 2
    float o[64];
#pragma unroll
    for (int j = 0; j < 64; j++) o[j] = C2v[j];
    for (int k = 0; k < 64; k += 4) {
        float h0 = row[k], h1 = row[k + 1], h2 = row[k + 2], h3 = row[k + 3];
        const float* w = W2s + k * 64;
#pragma unroll
        for (int j = 0; j < 64; j++) o[j] += h0 * w[j];
#pragma unroll
        for (int j = 0; j < 64; j++) o[j] += h1 * w[64 + j];
#pragma unroll
        for (int j = 0; j < 64; j++) o[j] += h2 * w[128 + j];
#pragma unroll
        for (int j = 0; j < 64; j++) o[j] += h3 * w[192 + j];
    }
#pragma unroll
    for (int j = 0; j < 64; j++) row[j] = fmaxf(o[j], 0.f);
    __syncthreads();
    // coalesced stage-out
    float4* o4 = (float4*)(xout + gbase);
    for (int i = tid; i < 2048; i += 128) {
        int r = i >> 4, c = (i & 15) * 4;
        if (row0 + r < NN) {
            const float* p = buf + r * 65 + c;
            float4 t; t.x = p[0]; t.y = p[1]; t.z = p[2]; t.w = p[3];
            o4[i] = t;
        }
    }
}

// ---------------- embedding gather + fused 2-layer MLP ----------------
__global__ __launch_bounds__(128) void embed_mlp2_kernel(
    const int* __restrict__ node_ids, const float* __restrict__ emb,
    const float* __restrict__ W1s, const float* __restrict__ C1v,
    const float* __restrict__ W2s, const float* __restrict__ C2v,
    float* __restrict__ xout)
{
    __shared__ float buf[128 * 65];
    int tid = threadIdx.x;
    int row0 = blockIdx.x * 128;
    int n = row0 + tid;
    float a[64];
#pragma unroll
    for (int j = 0; j < 64; j++) a[j] = C1v[j];
    if (n < NN) {
        long nid = node_ids[n];
        const float4* e4 = (const float4*)(emb + nid * 128);
        for (int q = 0; q < 32; q += 2) {
            float4 t0 = e4[q];
            float4 t1 = e4[q + 1];
            const float* w = W1s + q * 256;
#pragma unroll
            for (int j = 0; j < 64; j++) a[j] += t0.x * w[j];
#pragma unroll
            for (int j = 0; j < 64; j++) a[j] += t0.y * w[64 + j];
#pragma unroll
            for (int j = 0; j < 64; j++) a[j] += t0.z * w[128 + j];
#pragma unroll
            for (int j = 0; j < 64; j++) a[j] += t0.w * w[192 + j];
#pragma unroll
            for (int j = 0; j < 64; j++) a[j] += t1.x * w[256 + j];
#pragma unroll
            for (int j = 0; j < 64; j++) a[j] += t1.y * w[320 + j];
#pragma unroll
            for (int j = 0; j < 64; j++) a[j] += t1.z * w[384 + j];
#pragma unroll
            for (int j = 0; j < 64; j++) a[j] += t1.w * w[448 + j];
        }
    }
    float* row = buf + tid * 65;
#pragma unroll
    for (int j = 0; j < 64; j++) row[j] = fmaxf(a[j], 0.f);
    // layer 2
    float o[64];
#pragma unroll
    for (int j = 0; j < 64; j++) o[j] = C2v[j];
    for (int k = 0; k < 64; k += 4) {
        float h0 = row[k], h1 = row[k + 1], h2 = row[k + 2], h3 = row[k + 3];
        const float* w = W2s + k * 64;
#pragma unroll
        for (int j = 0; j < 64; j++) o[j] += h0 * w[j];
#pragma unroll
        for (int j = 0; j < 64; j++) o[j] += h1 * w[64 + j];
#pragma unroll
        for (int j = 0; j < 64; j++) o[j] += h2 * w[128 + j];
#pragma unroll
        for (int j = 0; j < 64; j++) o[j] += h3 * w[192 + j];
    }
#pragma unroll
    for (int j = 0; j < 64; j++) row[j] = fmaxf(o[j], 0.f);
    __syncthreads();
    long gbase = (long)row0 * 64;
    float4* o4 = (float4*)(xout + gbase);
    for (int i = tid; i < 2048; i += 128) {
        int r = i >> 4, c = (i & 15) * 4;
        if (row0 + r < NN) {
            const float* p = buf + r * 65 + c;
            float4 t; t.x = p[0]; t.y = p[1]; t.z = p[2]; t.w = p[3];
            o4[i] = t;
        }
    }
}

// ---------------- graph pooling over sorted batch (wave per node range) ----------------
#define POOL_WAVES 4096
#define POOL_CHUNK ((NN + POOL_WAVES - 1) / POOL_WAVES)
__global__ __launch_bounds__(256) void pool_kernel(
    const float* __restrict__ x, const int* __restrict__ batch,
    float* __restrict__ pooled, float* __restrict__ cnt)
{
    int wave = (blockIdx.x * blockDim.x + threadIdx.x) >> 6;
    int lane = threadIdx.x & 63;
    int start = wave * POOL_CHUNK;
    int end = start + POOL_CHUNK;
    if (end > NN) end = NN;
    if (start >= end) return;
    int g_cur = batch[start];
    float acc = 0.f, c = 0.f;
    for (int n = start; n < end; ++n) {
        int g = batch[n];
        if (g != g_cur) {
            unsafeAtomicAdd(&pooled[(long)g_cur * 64 + lane], acc);
            if (cnt != nullptr && lane == 0) unsafeAtomicAdd(&cnt[g_cur], c);
            acc = 0.f; c = 0.f; g_cur = g;
        }
        acc += x[(long)n * 64 + lane];
        c += 1.f;
    }
    unsafeAtomicAdd(&pooled[(long)g_cur * 64 + lane], acc);
    if (cnt != nullptr && lane == 0) unsafeAtomicAdd(&cnt[g_cur], c);
}

// ---------------- readout + softmax ----------------
__global__ void final_kernel(
    const float* __restrict__ pooled, const float* __restrict__ cnt,
    const float* __restrict__ linW, const float* __restrict__ linb,
    float* __restrict__ outp)
{
    int g = threadIdx.x;
    if (g >= GG) return;
    float z0 = 0.f, z1 = 0.f;
    float c = cnt[g];
    for (int l = 0; l < 4; l++) {
        const float* p = pooled + (long)l * GG * 64 + (long)g * 64;
        const float* W = linW + l * 128;
        float bscale = (l == 0) ? c : 1.f;   // layer0 bias summed per node; others once
        float s0 = linb[l * 2 + 0] * bscale;
        float s1 = linb[l * 2 + 1] * bscale;
        for (int k = 0; k < 64; k++) {
            float pk = p[k];
            s0 += pk * W[k * 2 + 0];
            s1 += pk * W[k * 2 + 1];
        }
        z0 += s0; z1 += s1;
    }
    float mx = fmaxf(z0, z1);
    float e0 = expf(z0 - mx), e1 = expf(z1 - mx);
    float inv = 1.f / (e0 + e1);
    outp[g * 2 + 0] = e0 * inv;
    outp[g * 2 + 1] = e1 * inv;
}

extern "C" void kernel_launch(void* const* d_in, const int* in_sizes, int n_in,
                              void* d_out, int out_size, void* d_ws, size_t ws_size,
                              hipStream_t stream) {
    const int*   node_ids = (const int*)d_in[0];
    const int*   edges    = (const int*)d_in[1];
    const int*   batch    = (const int*)d_in[2];
    const float* emb      = (const float*)d_in[3];
    const float* fh_W1 = (const float*)d_in[4];
    const float* fh_b1 = (const float*)d_in[5];
    const float* fh_g1 = (const float*)d_in[6];
    const float* fh_bt1 = (const float*)d_in[7];
    const float* fh_m1 = (const float*)d_in[8];
    const float* fh_v1 = (const float*)d_in[9];
    const float* fh_W2 = (const float*)d_in[10];
    const float* fh_b2 = (const float*)d_in[11];
    const float* fh_g2 = (const float*)d_in[12];
    const float* fh_bt2 = (const float*)d_in[13];
    const float* fh_m2 = (const float*)d_in[14];
    const float* fh_v2 = (const float*)d_in[15];
    const float* cW1 = (const float*)d_in[16];
    const float* cb1 = (const float*)d_in[17];
    const float* cg1 = (const float*)d_in[18];
    const float* cbt1 = (const float*)d_in[19];
    const float* cm1 = (const float*)d_in[20];
    const float* cv1 = (const float*)d_in[21];
    const float* cW2 = (const float*)d_in[22];
    const float* cb2 = (const float*)d_in[23];
    const float* cg2 = (const float*)d_in[24];
    const float* cbt2 = (const float*)d_in[25];
    const float* cm2 = (const float*)d_in[26];
    const float* cv2 = (const float*)d_in[27];
    const float* linW = (const float*)d_in[28];
    const float* linb = (const float*)d_in[29];

    float* ws = (float*)d_ws;
    int* cursor = (int*)(ws + CUR_OFF);
    int* col    = (int*)(ws + COL_OFF);
    int* bsum   = (int*)(ws + BSUM_OFF);

    prep_kernel<<<8, 256, 0, stream>>>(
        fh_W1, fh_b1, fh_g1, fh_bt1, fh_m1, fh_v1,
        fh_W2, fh_b2, fh_g2, fh_bt2, fh_m2, fh_v2,
        cW1, cb1, cg1, cbt1, cm1, cv1,
        cW2, cb2, cg2, cbt2, cm2, cv2, ws);

    // zero pooled + cnt, and the CSR histogram counters
    hipMemsetAsync(ws + POOL_OFF, 0, (4L * GG * 64 + GG) * sizeof(float), stream);
    hipMemsetAsync(cursor, 0, NN * sizeof(int), stream);

    // CSR build (dst-indexed)
    hist_kernel<<<(EE + 255) / 256, 256, 0, stream>>>(edges, cursor);
    scan_pass1<<<SCAN_NBLK, SCAN_BLK, 0, stream>>>(cursor, bsum);
    scan_pass2<<<1, 128, 0, stream>>>(bsum);
    scan_pass3<<<SCAN_NBLK, SCAN_BLK, 0, stream>>>(cursor, bsum);
    fill_kernel<<<(EE + 255) / 256, 256, 0, stream>>>(edges, cursor, col);

    const int NBLK128 = (NN + 127) / 128;

    embed_mlp2_kernel<<<NBLK128, 128, 0, stream>>>(
        node_ids, emb, ws + WT1_OFF, ws + C1_OFF, ws + WT2_OFF, ws + C2_OFF, ws + X_OFF);

    pool_kernel<<<POOL_WAVES / 4, 256, 0, stream>>>(
        ws + X_OFF, batch, ws + POOL_OFF, ws + CNT_OFF);

    for (int l = 0; l < LL; l++) {
        gather_kernel<<<(NN * 64 + 255) / 256, 256, 0, stream>>>(
            ws + X_OFF, cursor, col, ws + AGG_OFF);
        conv_mlp2_kernel<<<NBLK128, 128, 0, stream>>>(
            ws + AGG_OFF,
            ws + WTC1_OFF + l * 4096, ws + CC1_OFF + l * 64,
            ws + WTC2_OFF + l * 4096, ws + CC2_OFF + l * 64,
            ws + X_OFF);
        pool_kernel<<<POOL_WAVES / 4, 256, 0, stream>>>(
            ws + X_OFF, batch, ws + POOL_OFF + (long)(l + 1) * GG * 64, nullptr);
    }

    final_kernel<<<1, 128, 0, stream>>>(
        ws + POOL_OFF, ws + CNT_OFF, linW, linb, (float*)d_out);
}